// Round 4
// baseline (144.792 us; speedup 1.0000x reference)
//
#include <hip/hip_runtime.h>
#include <stdint.h>
#include <stddef.h>

// Problem constants (match reference setup_inputs)
static constexpr int Bb = 2;      // batch
static constexpr int Mq = 4096;   // queries per batch
static constexpr int Cc = 256;    // channels (dot K)
static constexpr int Hh = 64, Ww = 64;
static constexpr int Np = Hh * Ww;     // 4096 pixels (level 0)
static constexpr int NL1 = 1024;       // 32*32 pooled (level-1) pixels
static constexpr int RAD = 4;
static constexpr int SIDE = 2 * RAD + 1;     // 9
static constexpr int KPL = SIDE * SIDE;      // 81
static constexpr int NLVL = 4;
static constexpr int KTOT = NLVL * KPL;      // 324

// Workspace layout (bytes). Per query: 4 levels x 100 fp32 window taps.
static constexpr size_t WINBUF_B = 0;                                     // 13.1 MB fp32
static constexpr size_t ABF_B    = WINBUF_B + (size_t)Bb * Mq * 400 * 4;  // +4.2 MB bf16
static constexpr size_t BT_B     = ABF_B + (size_t)Bb * Mq * Cc * 2;      // +4.2 MB bf16
static constexpr size_t B1T_B    = BT_B + (size_t)Bb * Np * Cc * 2;       // +1.05 MB bf16
static constexpr size_t B2T_B    = B1T_B + (size_t)Bb * NL1 * Cc * 2;     // +256 KB bf16
static constexpr size_t B3T_B    = B2T_B + (size_t)Bb * 256 * Cc * 2;     // +64 KB bf16

typedef float floatx4 __attribute__((ext_vector_type(4)));
typedef short shortx8 __attribute__((ext_vector_type(8)));

union BfPack {
    shortx8 v;
    unsigned short u[8];
};

// fp32 -> bf16 round-to-nearest-even (finite inputs only)
__device__ __forceinline__ unsigned short f2bf(float f) {
    unsigned int x = __float_as_uint(f);
    x += 0x7fffu + ((x >> 16) & 1u);
    return (unsigned short)(x >> 16);
}

__device__ __forceinline__ float bf2f(unsigned short u) {
    return __uint_as_float((unsigned int)u << 16);
}

// ---------------------------------------------------------------------------
// Merged prep (unchanged, verified):
//   blocks [0,1024)    : fmap1 fp32 -> Abf bf16 (same layout)
//   blocks [1024,1280) : fmap2 (b,c,p) -> Bt (b,p,c) bf16  AND
//                        2x2-pooled B1t (b, y1*32+x1, c) bf16.
// ---------------------------------------------------------------------------
__global__ __launch_bounds__(256)
void cvt_kernel(const float* __restrict__ f1, const float* __restrict__ f2,
                unsigned short* __restrict__ Abf, unsigned short* __restrict__ Bt,
                unsigned short* __restrict__ B1t)
{
    __shared__ float tile[64 * 132];   // [channel][2 rows * 64 px], pad 132
    const int tid = threadIdx.x;
    if (blockIdx.x < 1024) {
        const int t = blockIdx.x * 256 + tid;      // 262144 threads x 8 elems
        const float4 v0 = *(const float4*)(f1 + (size_t)t * 8);
        const float4 v1 = *(const float4*)(f1 + (size_t)t * 8 + 4);
        BfPack p;
        p.u[0] = f2bf(v0.x); p.u[1] = f2bf(v0.y);
        p.u[2] = f2bf(v0.z); p.u[3] = f2bf(v0.w);
        p.u[4] = f2bf(v1.x); p.u[5] = f2bf(v1.y);
        p.u[6] = f2bf(v1.z); p.u[7] = f2bf(v1.w);
        *(shortx8*)(Abf + (size_t)t * 8) = p.v;
        return;
    }
    const int bid  = blockIdx.x - 1024;            // 0..255
    const int b    = bid >> 7;                     // batch
    const int cblk = (bid >> 5) & 3;               // 64-channel block
    const int y1   = bid & 31;                     // pooled row = image rows 2y1,2y1+1

    // load 64 channels x 128 px (rows 2y1, 2y1+1), coalesced along p
#pragma unroll
    for (int i = 0; i < 8; ++i) {
        const int v  = i * 256 + tid;              // 0..2047 float4 slots
        const int c  = v >> 5;                     // 0..63
        const int f4 = v & 31;                     // 0..31
        *(float4*)&tile[c * 132 + f4 * 4] =
            *(const float4*)&f2[((size_t)(b * Cc + cblk * 64 + c)) * Np + y1 * 128 + f4 * 4];
    }
    __syncthreads();

    // Bt: full-res transpose, 16 B bf16 per write
#pragma unroll
    for (int i = 0; i < 4; ++i) {
        const int w  = i * 256 + tid;
        const int rp = w >> 3;                     // 0..127 (px within row pair)
        const int cg = w & 7;
        BfPack p;
#pragma unroll
        for (int u = 0; u < 8; ++u)
            p.u[u] = f2bf(tile[(cg * 8 + u) * 132 + rp]);
        *(shortx8*)&Bt[((size_t)(b * Np + y1 * 128 + rp)) * Cc + cblk * 64 + cg * 8] = p.v;
    }

    // B1t: 2x2 pooled transpose (pooling commutes with the channel contraction)
    {
        const int x1 = tid >> 3;                   // 0..31
        const int cg = tid & 7;
        BfPack p;
#pragma unroll
        for (int u = 0; u < 8; ++u) {
            const int c = cg * 8 + u;
            const float v = 0.25f * (tile[c * 132 + 2 * x1]      + tile[c * 132 + 2 * x1 + 1]
                                   + tile[c * 132 + 64 + 2 * x1] + tile[c * 132 + 64 + 2 * x1 + 1]);
            p.u[u] = f2bf(v);
        }
        *(shortx8*)&B1t[((size_t)(b * NL1 + y1 * 32 + x1)) * Cc + cblk * 64 + cg * 8] = p.v;
    }
}

// ---------------------------------------------------------------------------
// Pool B1t -> B2t (16x16) and B3t (8x8). Pooling commutes with the dot, so
// level-2/3 corr windows become tiny GEMMs against these. fp32 accumulate,
// single bf16 round.
// ---------------------------------------------------------------------------
__global__ __launch_bounds__(256)
void pool23_kernel(const unsigned short* __restrict__ B1t,
                   unsigned short* __restrict__ B2t,
                   unsigned short* __restrict__ B3t)
{
    const int idx = blockIdx.x * 256 + threadIdx.x;
    if (idx < Bb * 256 * 32) {                 // B2: 16384 items (8 ch each)
        const int cg = idx & 31;
        const int p2 = (idx >> 5) & 255;
        const int b  = idx >> 13;
        const int y2 = p2 >> 4, x2 = p2 & 15;
        float s[8] = {0,0,0,0,0,0,0,0};
#pragma unroll
        for (int dy = 0; dy < 2; ++dy)
#pragma unroll
            for (int dx = 0; dx < 2; ++dx) {
                const int p1 = (2 * y2 + dy) * 32 + 2 * x2 + dx;
                BfPack v;
                v.v = *(const shortx8*)&B1t[((size_t)b * NL1 + p1) * Cc + cg * 8];
#pragma unroll
                for (int u = 0; u < 8; ++u) s[u] += bf2f(v.u[u]);
            }
        BfPack o;
#pragma unroll
        for (int u = 0; u < 8; ++u) o.u[u] = f2bf(0.25f * s[u]);
        *(shortx8*)&B2t[((size_t)b * 256 + p2) * Cc + cg * 8] = o.v;
    } else if (idx < Bb * 256 * 32 + Bb * 64 * 32) {   // B3: 4096 items
        const int i = idx - Bb * 256 * 32;
        const int cg = i & 31;
        const int p3 = (i >> 5) & 63;
        const int b  = i >> 11;
        const int y3 = p3 >> 3, x3 = p3 & 7;
        float s[8] = {0,0,0,0,0,0,0,0};
#pragma unroll
        for (int dy = 0; dy < 4; ++dy)
#pragma unroll
            for (int dx = 0; dx < 4; ++dx) {
                const int p1 = (4 * y3 + dy) * 32 + 4 * x3 + dx;
                BfPack v;
                v.v = *(const shortx8*)&B1t[((size_t)b * NL1 + p1) * Cc + cg * 8];
#pragma unroll
                for (int u = 0; u < 8; ++u) s[u] += bf2f(v.u[u]);
            }
        BfPack o;
#pragma unroll
        for (int u = 0; u < 8; ++u) o.u[u] = f2bf(0.0625f * s[u]);
        *(shortx8*)&B3t[((size_t)b * 64 + p3) * Cc + cg * 8] = o.v;
    }
}

// ---------------------------------------------------------------------------
// All-level window taps via MFMA with DIRECT L2 B-gathers (no region LDS).
// Levels 0/1: cell-binned (4x4 cells in level grid; windows live in a 13x13
// region). Levels 2/3: grids are tiny (256/64 px) -> full-grid per 64-query
// chunk. Per 16-query chunk: C[16q x region] = A x Bl^T, 16x16x32 bf16 MFMA,
// B-fragments gathered straight from L2-resident Blt. Epilogue scatters taps
// with 0<=wy,wx<10 into winbuf[q][lvl*100 + wy*10 + wx].
// ---------------------------------------------------------------------------
__global__ __launch_bounds__(512)
void win4_kernel(const unsigned short* __restrict__ Abf, // (Bb*Mq, Cc)
                 const unsigned short* __restrict__ B0t, // (Bb*4096, Cc)
                 const unsigned short* __restrict__ B1t, // (Bb*1024, Cc)
                 const unsigned short* __restrict__ B2t, // (Bb*256, Cc)
                 const unsigned short* __restrict__ B3t, // (Bb*64, Cc)
                 const float* __restrict__ cent,         // (Bb*Mq, 2)
                 float* __restrict__ winbuf)             // (Bb*Mq, 400)
{
    __shared__ int qlist[128];
    __shared__ int qx0s[128], qy0s[128];
    __shared__ int qcnt;

    const int tid  = threadIdx.x;
    const int wave = tid >> 6;
    const int lane = tid & 63;
    const int lane15 = lane & 15;
    const int quad   = lane >> 4;
    const int bidx = blockIdx.x;

    int lvl, b, cell = 0, q0 = 0;
    bool binned;
    if (bidx < 512)      { lvl = 0; binned = true;  b = bidx >> 8;          cell = bidx & 255; }
    else if (bidx < 640) { lvl = 1; binned = true;  b = (bidx - 512) >> 6;  cell = (bidx - 512) & 63; }
    else if (bidx < 768) { lvl = 2; binned = false; b = (bidx - 640) >> 6;  q0 = ((bidx - 640) & 63) * 64; }
    else                 { lvl = 3; binned = false; b = (bidx - 768) >> 6;  q0 = ((bidx - 768) & 63) * 64; }

    const int w   = Ww >> lvl;
    const int npx = w * w;
    const float scale = 1.0f / (float)(1 << lvl);
    const unsigned short* Bl = (lvl == 0) ? B0t : (lvl == 1) ? B1t : (lvl == 2) ? B2t : B3t;

    int xmin = 0, ymin = 0, rh = w, rw = w, rstride = w, ntile = npx >> 4;
    int cnt;

    if (binned) {
        const int ncx  = w >> 2;                   // cells per axis (16 or 8)
        const int binx = cell & (ncx - 1);
        const int biny = cell >> (4 - lvl);        // L0: >>4, L1: >>3
        xmin = 4 * binx - 4; if (xmin < 0) xmin = 0;
        ymin = 4 * biny - 4; if (ymin < 0) ymin = 0;
        int xmax = 4 * binx + 8; if (xmax > w - 1) xmax = w - 1;
        int ymax = 4 * biny + 8; if (ymax > w - 1) ymax = w - 1;
        rh = ymax - ymin + 1; rw = xmax - xmin + 1;
        rstride = 13;
        ntile = (rh * 13 + 15) >> 4;

        if (tid == 0) qcnt = 0;
        __syncthreads();
#pragma unroll
        for (int i = 0; i < 8; ++i) {
            const int m = i * 512 + tid;
            const float2 cc = *(const float2*)&cent[((size_t)b * Mq + m) * 2];
            const int fx = (int)floorf(cc.x * scale);
            const int fy = (int)floorf(cc.y * scale);
            if ((fx >> 2) == binx && (fy >> 2) == biny) {
                const int idx = atomicAdd(&qcnt, 1);
                if (idx < 128) {
                    qlist[idx] = m;
                    qx0s[idx] = fx - RAD;
                    qy0s[idx] = fy - RAD;
                }
            }
        }
        __syncthreads();
        cnt = qcnt < 128 ? qcnt : 128;
    } else {
        if (tid < 64) {
            const int m = q0 + tid;
            const float2 cc = *(const float2*)&cent[((size_t)b * Mq + m) * 2];
            qlist[tid] = m;
            qx0s[tid] = (int)floorf(cc.x * scale) - RAD;
            qy0s[tid] = (int)floorf(cc.y * scale) - RAD;
        }
        __syncthreads();
        cnt = 64;
    }

    // tile -> pixel mapping (lane-level), clamped addresses for dead lanes
    const int jt0 = wave, jt1 = wave + 8;
    const bool t0ok = jt0 < ntile;
    const bool t1ok = jt1 < ntile;
    int y0 = ymin, x0 = xmin, y1 = ymin, x1 = xmin;
    bool v0 = false, v1 = false;
    {
        const int px = jt0 * 16 + lane15;
        int py = (rstride == 13) ? ((px * 5043) >> 16) : (px >> (6 - lvl));
        const int pxx = px - py * rstride;
        v0 = t0ok && (py < rh) && (pxx < rw);
        if (py > rh - 1) py = rh - 1;
        const int pxc = pxx < rw ? pxx : rw - 1;
        y0 = ymin + py; x0 = xmin + pxc;
    }
    {
        const int px = jt1 * 16 + lane15;
        int py = (rstride == 13) ? ((px * 5043) >> 16) : (px >> (6 - lvl));
        const int pxx = px - py * rstride;
        v1 = t1ok && (py < rh) && (pxx < rw);
        if (py > rh - 1) py = rh - 1;
        const int pxc = pxx < rw ? pxx : rw - 1;
        y1 = ymin + py; x1 = xmin + pxc;
    }
    const size_t bB = (size_t)b * npx * Cc;
    const size_t off0 = bB + (size_t)(y0 * w + x0) * Cc + quad * 8;
    const size_t off1 = bB + (size_t)(y1 * w + x1) * Cc + quad * 8;

    for (int m0 = 0; m0 < cnt; m0 += 16) {
        // A fragments: lane15 -> query row, quad -> k-subchunk
        const int qidx = (m0 + lane15) < cnt ? (m0 + lane15) : (cnt - 1);
        const unsigned short* arow = Abf + (size_t)(b * Mq + qlist[qidx]) * Cc + quad * 8;
        shortx8 afr[8];
#pragma unroll
        for (int k0 = 0; k0 < 8; ++k0)
            afr[k0] = *(const shortx8*)&arow[k0 * 32];

        floatx4 acc0 = {0.f, 0.f, 0.f, 0.f};
        floatx4 acc1 = {0.f, 0.f, 0.f, 0.f};
#pragma unroll
        for (int k0 = 0; k0 < 8; ++k0) {
            if (t0ok) {
                const shortx8 b0 = *(const shortx8*)&Bl[off0 + k0 * 32];
                acc0 = __builtin_amdgcn_mfma_f32_16x16x32_bf16(afr[k0], b0, acc0, 0, 0, 0);
            }
            if (t1ok) {
                const shortx8 b1 = *(const shortx8*)&Bl[off1 + k0 * 32];
                acc1 = __builtin_amdgcn_mfma_f32_16x16x32_bf16(afr[k0], b1, acc1, 0, 0, 0);
            }
        }

        // scatter: C layout col=lane15, row=quad*4+reg (m89/m91 verified)
#pragma unroll
        for (int t = 0; t < 2; ++t) {
            const bool vv = (t == 0) ? v0 : v1;
            if (!vv) continue;
            const floatx4 a = (t == 0) ? acc0 : acc1;
            const int yy = (t == 0) ? y0 : y1;
            const int xx = (t == 0) ? x0 : x1;
#pragma unroll
            for (int r = 0; r < 4; ++r) {
                const int qi = m0 + quad * 4 + r;
                if (qi < cnt) {
                    const int wy = yy - qy0s[qi];
                    const int wx = xx - qx0s[qi];
                    if ((unsigned)wy < 10u && (unsigned)wx < 10u)
                        winbuf[((size_t)b * Mq + qlist[qi]) * 400 + lvl * 100 + wy * 10 + wx] = a[r];
                }
            }
        }
    }
}

// ---------------------------------------------------------------------------
// Sampler: 8 queries/block. Loads the 4 per-level 10x10 windows (1.6 KB/query)
// and emits all 324 bilinear outputs per query. No pooling work left.
// ---------------------------------------------------------------------------
__global__ __launch_bounds__(256)
void pyr_sample_kernel(const float* __restrict__ cent,     // (Bb*Mq, 2)
                       const float* __restrict__ winbuf,   // (Bb*Mq, 400)
                       float* __restrict__ out)            // (Bb, 324, Mq)
{
    __shared__ float win[8][400];
    __shared__ float qcx[8], qcy[8];
    __shared__ int qx0l[8][4], qy0l[8][4];

    const int tid = threadIdx.x;
    const int b   = blockIdx.x >> 9;           // 512 blocks per batch
    const int m0  = (blockIdx.x & 511) * 8;
    const size_t gq0 = (size_t)(b * Mq + m0);

    if (tid < 32) {
        const int q = tid >> 2, l = tid & 3;
        const float cx = cent[(gq0 + q) * 2 + 0];
        const float cy = cent[(gq0 + q) * 2 + 1];
        if (l == 0) { qcx[q] = cx; qcy[q] = cy; }
        const float scl = 1.0f / (float)(1 << l);
        qx0l[q][l] = (int)floorf(cx * scl) - RAD;
        qy0l[q][l] = (int)floorf(cy * scl) - RAD;
    }
    // load windows: 8 queries x 100 float4
    for (int v = tid; v < 800; v += 256) {
        const int q = (v * 41) >> 12;          // v/100 for v<800
        const int o = v - q * 100;
        *(float4*)&win[q][o * 4] = *(const float4*)&winbuf[(gq0 + q) * 400 + o * 4];
    }
    __syncthreads();

    // sampling: 324*8 = 2592 outputs
    for (int i = 0; i < 11; ++i) {
        const int idx = i * 256 + tid;
        if (idx >= KTOT * 8) break;
        const int q  = idx & 7;
        const int kk = idx >> 3;           // 0..323
        const int lvl = kk / KPL;
        const int r   = kk - lvl * KPL;
        const int di  = r / SIDE;          // x-offset index
        const int dj  = r - di * SIDE;     // y-offset index

        const int w = Ww >> lvl;
        const float scale = 1.0f / (float)(1 << lvl);
        const float x = qcx[q] * scale + (float)(di - RAD);
        const float y = qcy[q] * scale + (float)(dj - RAD);

        const float x0f = floorf(x), y0f = floorf(y);
        const float wx1 = x - x0f, wx0 = 1.0f - wx1;
        const float wy1 = y - y0f, wy0 = 1.0f - wy1;
        const float fmx = (float)(w - 1);
        const bool vx0 = (x0f >= 0.0f) && (x0f <= fmx);
        const bool vx1 = (x0f + 1.0f >= 0.0f) && (x0f + 1.0f <= fmx);
        const bool vy0 = (y0f >= 0.0f) && (y0f <= fmx);
        const bool vy1 = (y0f + 1.0f >= 0.0f) && (y0f + 1.0f <= fmx);

        const int ix0 = (int)x0f, iy0 = (int)y0f;

        const float* buf = &win[q][lvl * 100];
        const int ox = qx0l[q][lvl], oy = qy0l[q][lvl];
        const int cx0 = ix0 - ox, cx1 = cx0 + 1;
        const int cy0r = iy0 - oy, cy1r = cy0r + 1;
        const float g00 = (vx0 && vy0) ? buf[cy0r * 10 + cx0] : 0.0f;
        const float g10 = (vx1 && vy0) ? buf[cy0r * 10 + cx1] : 0.0f;
        const float g01 = (vx0 && vy1) ? buf[cy1r * 10 + cx0] : 0.0f;
        const float g11 = (vx1 && vy1) ? buf[cy1r * 10 + cx1] : 0.0f;

        out[((size_t)b * KTOT + kk) * Mq + m0 + q] =
            wy0 * (wx0 * g00 + wx1 * g10) + wy1 * (wx0 * g01 + wx1 * g11);
    }
}

extern "C" void kernel_launch(void* const* d_in, const int* in_sizes, int n_in,
                              void* d_out, int out_size, void* d_ws, size_t ws_size,
                              hipStream_t stream)
{
    const float* fmap1 = (const float*)d_in[0];   // (Bb, Mq, Cc)
    const float* fmap2 = (const float*)d_in[1];   // (Bb, Cc, Hh, Ww)
    const float* cent  = (const float*)d_in[2];   // (Bb, Mq, 2)
    char* ws = (char*)d_ws;
    float* winbuf = (float*)(ws + WINBUF_B);
    unsigned short* Abf = (unsigned short*)(ws + ABF_B);
    unsigned short* Bt  = (unsigned short*)(ws + BT_B);
    unsigned short* B1t = (unsigned short*)(ws + B1T_B);
    unsigned short* B2t = (unsigned short*)(ws + B2T_B);
    unsigned short* B3t = (unsigned short*)(ws + B3T_B);
    float* out = (float*)d_out;

    // 0) merged prep: A cvt (1024 blocks) + B transpose/cvt + pooled B1t (256)
    cvt_kernel<<<1280, 256, 0, stream>>>(fmap1, fmap2, Abf, Bt, B1t);

    // 1) pool B1t -> B2t, B3t (tiny)
    pool23_kernel<<<80, 256, 0, stream>>>(B1t, B2t, B3t);

    // 2) all-level window taps: L0/L1 cell-binned, L2/L3 full-grid chunks
    win4_kernel<<<896, 512, 0, stream>>>(Abf, Bt, B1t, B2t, B3t, cent, winbuf);

    // 3) bilinear sampling from the 4 windows
    pyr_sample_kernel<<<Bb * Mq / 8, 256, 0, stream>>>(cent, winbuf, out);
}

// Round 5
// 131.990 us; speedup vs baseline: 1.0970x; 1.0970x over previous
//
#include <hip/hip_runtime.h>
#include <stdint.h>
#include <stddef.h>

// Problem constants (match reference setup_inputs)
static constexpr int Bb = 2;      // batch
static constexpr int Mq = 4096;   // queries per batch
static constexpr int Cc = 256;    // channels (dot K)
static constexpr int Hh = 64, Ww = 64;
static constexpr int Np = Hh * Ww;     // 4096 pixels (level 0)
static constexpr int NL1 = 1024;       // 32*32 pooled (level-1) pixels
static constexpr int RAD = 4;
static constexpr int SIDE = 2 * RAD + 1;     // 9
static constexpr int KPL = SIDE * SIDE;      // 81
static constexpr int NLVL = 4;
static constexpr int KTOT = NLVL * KPL;      // 324

// Workspace layout (bytes). Per query: 4 levels x 100 fp32 window taps.
static constexpr size_t WINBUF_B = 0;                                     // 13.1 MB fp32
static constexpr size_t ABF_B    = WINBUF_B + (size_t)Bb * Mq * 400 * 4;  // +4.2 MB bf16
static constexpr size_t BT_B     = ABF_B + (size_t)Bb * Mq * Cc * 2;      // +4.2 MB bf16
static constexpr size_t B1T_B    = BT_B + (size_t)Bb * Np * Cc * 2;       // +1.05 MB bf16
static constexpr size_t B2T_B    = B1T_B + (size_t)Bb * NL1 * Cc * 2;     // +256 KB bf16
static constexpr size_t B3T_B    = B2T_B + (size_t)Bb * 256 * Cc * 2;     // +64 KB bf16

typedef float floatx4 __attribute__((ext_vector_type(4)));
typedef short shortx8 __attribute__((ext_vector_type(8)));

union BfPack {
    shortx8 v;
    unsigned short u[8];
};

// fp32 -> bf16 round-to-nearest-even (finite inputs only)
__device__ __forceinline__ unsigned short f2bf(float f) {
    unsigned int x = __float_as_uint(f);
    x += 0x7fffu + ((x >> 16) & 1u);
    return (unsigned short)(x >> 16);
}

__device__ __forceinline__ float bf2f(unsigned short u) {
    return __uint_as_float((unsigned int)u << 16);
}

// ---------------------------------------------------------------------------
// Merged prep (unchanged, verified):
//   blocks [0,1024)    : fmap1 fp32 -> Abf bf16 (same layout)
//   blocks [1024,1280) : fmap2 (b,c,p) -> Bt (b,p,c) bf16  AND
//                        2x2-pooled B1t (b, y1*32+x1, c) bf16.
// ---------------------------------------------------------------------------
__global__ __launch_bounds__(256)
void cvt_kernel(const float* __restrict__ f1, const float* __restrict__ f2,
                unsigned short* __restrict__ Abf, unsigned short* __restrict__ Bt,
                unsigned short* __restrict__ B1t)
{
    __shared__ float tile[64 * 132];   // [channel][2 rows * 64 px], pad 132
    const int tid = threadIdx.x;
    if (blockIdx.x < 1024) {
        const int t = blockIdx.x * 256 + tid;      // 262144 threads x 8 elems
        const float4 v0 = *(const float4*)(f1 + (size_t)t * 8);
        const float4 v1 = *(const float4*)(f1 + (size_t)t * 8 + 4);
        BfPack p;
        p.u[0] = f2bf(v0.x); p.u[1] = f2bf(v0.y);
        p.u[2] = f2bf(v0.z); p.u[3] = f2bf(v0.w);
        p.u[4] = f2bf(v1.x); p.u[5] = f2bf(v1.y);
        p.u[6] = f2bf(v1.z); p.u[7] = f2bf(v1.w);
        *(shortx8*)(Abf + (size_t)t * 8) = p.v;
        return;
    }
    const int bid  = blockIdx.x - 1024;            // 0..255
    const int b    = bid >> 7;                     // batch
    const int cblk = (bid >> 5) & 3;               // 64-channel block
    const int y1   = bid & 31;                     // pooled row = image rows 2y1,2y1+1

    // load 64 channels x 128 px (rows 2y1, 2y1+1), coalesced along p
#pragma unroll
    for (int i = 0; i < 8; ++i) {
        const int v  = i * 256 + tid;              // 0..2047 float4 slots
        const int c  = v >> 5;                     // 0..63
        const int f4 = v & 31;                     // 0..31
        *(float4*)&tile[c * 132 + f4 * 4] =
            *(const float4*)&f2[((size_t)(b * Cc + cblk * 64 + c)) * Np + y1 * 128 + f4 * 4];
    }
    __syncthreads();

    // Bt: full-res transpose, 16 B bf16 per write
#pragma unroll
    for (int i = 0; i < 4; ++i) {
        const int w  = i * 256 + tid;
        const int rp = w >> 3;                     // 0..127 (px within row pair)
        const int cg = w & 7;
        BfPack p;
#pragma unroll
        for (int u = 0; u < 8; ++u)
            p.u[u] = f2bf(tile[(cg * 8 + u) * 132 + rp]);
        *(shortx8*)&Bt[((size_t)(b * Np + y1 * 128 + rp)) * Cc + cblk * 64 + cg * 8] = p.v;
    }

    // B1t: 2x2 pooled transpose (pooling commutes with the channel contraction)
    {
        const int x1 = tid >> 3;                   // 0..31
        const int cg = tid & 7;
        BfPack p;
#pragma unroll
        for (int u = 0; u < 8; ++u) {
            const int c = cg * 8 + u;
            const float v = 0.25f * (tile[c * 132 + 2 * x1]      + tile[c * 132 + 2 * x1 + 1]
                                   + tile[c * 132 + 64 + 2 * x1] + tile[c * 132 + 64 + 2 * x1 + 1]);
            p.u[u] = f2bf(v);
        }
        *(shortx8*)&B1t[((size_t)(b * NL1 + y1 * 32 + x1)) * Cc + cblk * 64 + cg * 8] = p.v;
    }
}

// ---------------------------------------------------------------------------
// Pool B1t -> B2t (16x16) and B3t (8x8).  (unchanged, verified)
// ---------------------------------------------------------------------------
__global__ __launch_bounds__(256)
void pool23_kernel(const unsigned short* __restrict__ B1t,
                   unsigned short* __restrict__ B2t,
                   unsigned short* __restrict__ B3t)
{
    const int idx = blockIdx.x * 256 + threadIdx.x;
    if (idx < Bb * 256 * 32) {                 // B2: 16384 items (8 ch each)
        const int cg = idx & 31;
        const int p2 = (idx >> 5) & 255;
        const int b  = idx >> 13;
        const int y2 = p2 >> 4, x2 = p2 & 15;
        float s[8] = {0,0,0,0,0,0,0,0};
#pragma unroll
        for (int dy = 0; dy < 2; ++dy)
#pragma unroll
            for (int dx = 0; dx < 2; ++dx) {
                const int p1 = (2 * y2 + dy) * 32 + 2 * x2 + dx;
                BfPack v;
                v.v = *(const shortx8*)&B1t[((size_t)b * NL1 + p1) * Cc + cg * 8];
#pragma unroll
                for (int u = 0; u < 8; ++u) s[u] += bf2f(v.u[u]);
            }
        BfPack o;
#pragma unroll
        for (int u = 0; u < 8; ++u) o.u[u] = f2bf(0.25f * s[u]);
        *(shortx8*)&B2t[((size_t)b * 256 + p2) * Cc + cg * 8] = o.v;
    } else if (idx < Bb * 256 * 32 + Bb * 64 * 32) {   // B3: 4096 items
        const int i = idx - Bb * 256 * 32;
        const int cg = i & 31;
        const int p3 = (i >> 5) & 63;
        const int b  = i >> 11;
        const int y3 = p3 >> 3, x3 = p3 & 7;
        float s[8] = {0,0,0,0,0,0,0,0};
#pragma unroll
        for (int dy = 0; dy < 4; ++dy)
#pragma unroll
            for (int dx = 0; dx < 4; ++dx) {
                const int p1 = (4 * y3 + dy) * 32 + 4 * x3 + dx;
                BfPack v;
                v.v = *(const shortx8*)&B1t[((size_t)b * NL1 + p1) * Cc + cg * 8];
#pragma unroll
                for (int u = 0; u < 8; ++u) s[u] += bf2f(v.u[u]);
            }
        BfPack o;
#pragma unroll
        for (int u = 0; u < 8; ++u) o.u[u] = f2bf(0.0625f * s[u]);
        *(shortx8*)&B3t[((size_t)b * 64 + p3) * Cc + cg * 8] = o.v;
    }
}

// ---------------------------------------------------------------------------
// All-level window taps via MFMA, REGISTER-RESIDENT B version.
// Same binning/scatter as the verified R4 kernel; the only change is load
// scheduling: the 16 B-fragments (m0-chunk-invariant!) are burst-loaded into
// VGPRs ONCE per block before the query-chunk loop (16 independent dwordx4
// gathers, one wait), and each chunk burst-loads its 8 A-fragments then runs
// 16 register-only MFMAs. Kills the load->wait->mfma serial chain (R4 had
// VGPR_Count=28: nothing register-resident, 58 us latency-bound).
// ---------------------------------------------------------------------------
__global__ __launch_bounds__(512)
void win4_kernel(const unsigned short* __restrict__ Abf, // (Bb*Mq, Cc)
                 const unsigned short* __restrict__ B0t, // (Bb*4096, Cc)
                 const unsigned short* __restrict__ B1t, // (Bb*1024, Cc)
                 const unsigned short* __restrict__ B2t, // (Bb*256, Cc)
                 const unsigned short* __restrict__ B3t, // (Bb*64, Cc)
                 const float* __restrict__ cent,         // (Bb*Mq, 2)
                 float* __restrict__ winbuf)             // (Bb*Mq, 400)
{
    __shared__ int qlist[128];
    __shared__ int qx0s[128], qy0s[128];
    __shared__ int qcnt;

    const int tid  = threadIdx.x;
    const int wave = tid >> 6;
    const int lane = tid & 63;
    const int lane15 = lane & 15;
    const int quad   = lane >> 4;
    const int bidx = blockIdx.x;

    int lvl, b, cell = 0, q0 = 0;
    bool binned;
    if (bidx < 512)      { lvl = 0; binned = true;  b = bidx >> 8;          cell = bidx & 255; }
    else if (bidx < 640) { lvl = 1; binned = true;  b = (bidx - 512) >> 6;  cell = (bidx - 512) & 63; }
    else if (bidx < 768) { lvl = 2; binned = false; b = (bidx - 640) >> 6;  q0 = ((bidx - 640) & 63) * 64; }
    else                 { lvl = 3; binned = false; b = (bidx - 768) >> 6;  q0 = ((bidx - 768) & 63) * 64; }

    const int w   = Ww >> lvl;
    const int npx = w * w;
    const float scale = 1.0f / (float)(1 << lvl);
    const unsigned short* Bl = (lvl == 0) ? B0t : (lvl == 1) ? B1t : (lvl == 2) ? B2t : B3t;

    int xmin = 0, ymin = 0, rh = w, rw = w, rstride = w, ntile = npx >> 4;
    int cnt;

    if (binned) {
        const int ncx  = w >> 2;                   // cells per axis (16 or 8)
        const int binx = cell & (ncx - 1);
        const int biny = cell >> (4 - lvl);        // L0: >>4, L1: >>3
        xmin = 4 * binx - 4; if (xmin < 0) xmin = 0;
        ymin = 4 * biny - 4; if (ymin < 0) ymin = 0;
        int xmax = 4 * binx + 8; if (xmax > w - 1) xmax = w - 1;
        int ymax = 4 * biny + 8; if (ymax > w - 1) ymax = w - 1;
        rh = ymax - ymin + 1; rw = xmax - xmin + 1;
        rstride = 13;
        ntile = (rh * 13 + 15) >> 4;

        if (tid == 0) qcnt = 0;
        __syncthreads();
#pragma unroll
        for (int i = 0; i < 8; ++i) {
            const int m = i * 512 + tid;
            const float2 cc = *(const float2*)&cent[((size_t)b * Mq + m) * 2];
            const int fx = (int)floorf(cc.x * scale);
            const int fy = (int)floorf(cc.y * scale);
            if ((fx >> 2) == binx && (fy >> 2) == biny) {
                const int idx = atomicAdd(&qcnt, 1);
                if (idx < 128) {
                    qlist[idx] = m;
                    qx0s[idx] = fx - RAD;
                    qy0s[idx] = fy - RAD;
                }
            }
        }
        __syncthreads();
        cnt = qcnt < 128 ? qcnt : 128;
    } else {
        if (tid < 64) {
            const int m = q0 + tid;
            const float2 cc = *(const float2*)&cent[((size_t)b * Mq + m) * 2];
            qlist[tid] = m;
            qx0s[tid] = (int)floorf(cc.x * scale) - RAD;
            qy0s[tid] = (int)floorf(cc.y * scale) - RAD;
        }
        __syncthreads();
        cnt = 64;
    }

    // tile -> pixel mapping (lane-level), clamped addresses for dead lanes
    const int jt0 = wave, jt1 = wave + 8;
    const bool t0ok = jt0 < ntile;
    const bool t1ok = jt1 < ntile;
    int y0 = ymin, x0 = xmin, y1 = ymin, x1 = xmin;
    bool v0 = false, v1 = false;
    {
        const int px = jt0 * 16 + lane15;
        int py = (rstride == 13) ? ((px * 5043) >> 16) : (px >> (6 - lvl));
        const int pxx = px - py * rstride;
        v0 = t0ok && (py < rh) && (pxx < rw);
        if (py > rh - 1) py = rh - 1;
        const int pxc = pxx < rw ? pxx : rw - 1;
        y0 = ymin + py; x0 = xmin + pxc;
    }
    {
        const int px = jt1 * 16 + lane15;
        int py = (rstride == 13) ? ((px * 5043) >> 16) : (px >> (6 - lvl));
        const int pxx = px - py * rstride;
        v1 = t1ok && (py < rh) && (pxx < rw);
        if (py > rh - 1) py = rh - 1;
        const int pxc = pxx < rw ? pxx : rw - 1;
        y1 = ymin + py; x1 = xmin + pxc;
    }
    const size_t bB = (size_t)b * npx * Cc;
    const unsigned short* bp0 = Bl + bB + (size_t)(y0 * w + x0) * Cc + quad * 8;
    const unsigned short* bp1 = Bl + bB + (size_t)(y1 * w + x1) * Cc + quad * 8;

    // ---- burst-load ALL B fragments into registers (once per block) ----
    shortx8 bfr0[8], bfr1[8];
#pragma unroll
    for (int k0 = 0; k0 < 8; ++k0)
        bfr0[k0] = *(const shortx8*)&bp0[k0 * 32];
#pragma unroll
    for (int k0 = 0; k0 < 8; ++k0)
        bfr1[k0] = *(const shortx8*)&bp1[k0 * 32];

    for (int m0 = 0; m0 < cnt; m0 += 16) {
        // A fragments: lane15 -> query row, quad -> k-subchunk (burst)
        const int qidx = (m0 + lane15) < cnt ? (m0 + lane15) : (cnt - 1);
        const unsigned short* arow = Abf + (size_t)(b * Mq + qlist[qidx]) * Cc + quad * 8;
        shortx8 afr[8];
#pragma unroll
        for (int k0 = 0; k0 < 8; ++k0)
            afr[k0] = *(const shortx8*)&arow[k0 * 32];

        // register-only MFMA chains
        floatx4 acc0 = {0.f, 0.f, 0.f, 0.f};
        floatx4 acc1 = {0.f, 0.f, 0.f, 0.f};
        if (t0ok) {
#pragma unroll
            for (int k0 = 0; k0 < 8; ++k0)
                acc0 = __builtin_amdgcn_mfma_f32_16x16x32_bf16(afr[k0], bfr0[k0], acc0, 0, 0, 0);
        }
        if (t1ok) {
#pragma unroll
            for (int k0 = 0; k0 < 8; ++k0)
                acc1 = __builtin_amdgcn_mfma_f32_16x16x32_bf16(afr[k0], bfr1[k0], acc1, 0, 0, 0);
        }

        // scatter: C layout col=lane15, row=quad*4+reg (m89/m91 verified)
#pragma unroll
        for (int t = 0; t < 2; ++t) {
            const bool vv = (t == 0) ? v0 : v1;
            if (!vv) continue;
            const floatx4 a = (t == 0) ? acc0 : acc1;
            const int yy = (t == 0) ? y0 : y1;
            const int xx = (t == 0) ? x0 : x1;
#pragma unroll
            for (int r = 0; r < 4; ++r) {
                const int qi = m0 + quad * 4 + r;
                if (qi < cnt) {
                    const int wy = yy - qy0s[qi];
                    const int wx = xx - qx0s[qi];
                    if ((unsigned)wy < 10u && (unsigned)wx < 10u)
                        winbuf[((size_t)b * Mq + qlist[qi]) * 400 + lvl * 100 + wy * 10 + wx] = a[r];
                }
            }
        }
    }
}

// ---------------------------------------------------------------------------
// Sampler: 8 queries/block. Loads the 4 per-level 10x10 windows (1.6 KB/query)
// and emits all 324 bilinear outputs per query.  (unchanged, verified)
// ---------------------------------------------------------------------------
__global__ __launch_bounds__(256)
void pyr_sample_kernel(const float* __restrict__ cent,     // (Bb*Mq, 2)
                       const float* __restrict__ winbuf,   // (Bb*Mq, 400)
                       float* __restrict__ out)            // (Bb, 324, Mq)
{
    __shared__ float win[8][400];
    __shared__ float qcx[8], qcy[8];
    __shared__ int qx0l[8][4], qy0l[8][4];

    const int tid = threadIdx.x;
    const int b   = blockIdx.x >> 9;           // 512 blocks per batch
    const int m0  = (blockIdx.x & 511) * 8;
    const size_t gq0 = (size_t)(b * Mq + m0);

    if (tid < 32) {
        const int q = tid >> 2, l = tid & 3;
        const float cx = cent[(gq0 + q) * 2 + 0];
        const float cy = cent[(gq0 + q) * 2 + 1];
        if (l == 0) { qcx[q] = cx; qcy[q] = cy; }
        const float scl = 1.0f / (float)(1 << l);
        qx0l[q][l] = (int)floorf(cx * scl) - RAD;
        qy0l[q][l] = (int)floorf(cy * scl) - RAD;
    }
    // load windows: 8 queries x 100 float4
    for (int v = tid; v < 800; v += 256) {
        const int q = (v * 41) >> 12;          // v/100 for v<800
        const int o = v - q * 100;
        *(float4*)&win[q][o * 4] = *(const float4*)&winbuf[(gq0 + q) * 400 + o * 4];
    }
    __syncthreads();

    // sampling: 324*8 = 2592 outputs
    for (int i = 0; i < 11; ++i) {
        const int idx = i * 256 + tid;
        if (idx >= KTOT * 8) break;
        const int q  = idx & 7;
        const int kk = idx >> 3;           // 0..323
        const int lvl = kk / KPL;
        const int r   = kk - lvl * KPL;
        const int di  = r / SIDE;          // x-offset index
        const int dj  = r - di * SIDE;     // y-offset index

        const int w = Ww >> lvl;
        const float scale = 1.0f / (float)(1 << lvl);
        const float x = qcx[q] * scale + (float)(di - RAD);
        const float y = qcy[q] * scale + (float)(dj - RAD);

        const float x0f = floorf(x), y0f = floorf(y);
        const float wx1 = x - x0f, wx0 = 1.0f - wx1;
        const float wy1 = y - y0f, wy0 = 1.0f - wy1;
        const float fmx = (float)(w - 1);
        const bool vx0 = (x0f >= 0.0f) && (x0f <= fmx);
        const bool vx1 = (x0f + 1.0f >= 0.0f) && (x0f + 1.0f <= fmx);
        const bool vy0 = (y0f >= 0.0f) && (y0f <= fmx);
        const bool vy1 = (y0f + 1.0f >= 0.0f) && (y0f + 1.0f <= fmx);

        const int ix0 = (int)x0f, iy0 = (int)y0f;

        const float* buf = &win[q][lvl * 100];
        const int ox = qx0l[q][lvl], oy = qy0l[q][lvl];
        const int cx0 = ix0 - ox, cx1 = cx0 + 1;
        const int cy0r = iy0 - oy, cy1r = cy0r + 1;
        const float g00 = (vx0 && vy0) ? buf[cy0r * 10 + cx0] : 0.0f;
        const float g10 = (vx1 && vy0) ? buf[cy0r * 10 + cx1] : 0.0f;
        const float g01 = (vx0 && vy1) ? buf[cy1r * 10 + cx0] : 0.0f;
        const float g11 = (vx1 && vy1) ? buf[cy1r * 10 + cx1] : 0.0f;

        out[((size_t)b * KTOT + kk) * Mq + m0 + q] =
            wy0 * (wx0 * g00 + wx1 * g10) + wy1 * (wx0 * g01 + wx1 * g11);
    }
}

extern "C" void kernel_launch(void* const* d_in, const int* in_sizes, int n_in,
                              void* d_out, int out_size, void* d_ws, size_t ws_size,
                              hipStream_t stream)
{
    const float* fmap1 = (const float*)d_in[0];   // (Bb, Mq, Cc)
    const float* fmap2 = (const float*)d_in[1];   // (Bb, Cc, Hh, Ww)
    const float* cent  = (const float*)d_in[2];   // (Bb, Mq, 2)
    char* ws = (char*)d_ws;
    float* winbuf = (float*)(ws + WINBUF_B);
    unsigned short* Abf = (unsigned short*)(ws + ABF_B);
    unsigned short* Bt  = (unsigned short*)(ws + BT_B);
    unsigned short* B1t = (unsigned short*)(ws + B1T_B);
    unsigned short* B2t = (unsigned short*)(ws + B2T_B);
    unsigned short* B3t = (unsigned short*)(ws + B3T_B);
    float* out = (float*)d_out;

    // 0) merged prep: A cvt (1024 blocks) + B transpose/cvt + pooled B1t (256)
    cvt_kernel<<<1280, 256, 0, stream>>>(fmap1, fmap2, Abf, Bt, B1t);

    // 1) pool B1t -> B2t, B3t (tiny)
    pool23_kernel<<<80, 256, 0, stream>>>(B1t, B2t, B3t);

    // 2) all-level window taps: L0/L1 cell-binned, L2/L3 full-grid chunks
    win4_kernel<<<896, 512, 0, stream>>>(Abf, Bt, B1t, B2t, B3t, cent, winbuf);

    // 3) bilinear sampling from the 4 windows
    pyr_sample_kernel<<<Bb * Mq / 8, 256, 0, stream>>>(cent, winbuf, out);
}